// Round 1
// baseline (1574.883 us; speedup 1.0000x reference)
//
#include <hip/hip_runtime.h>
#include <math.h>

#define NPTS   4096
#define NB     8
#define M1     1024     // ceil(0.25*4096)
#define M2     820      // ceil(0.2*4096)
#define NEXTRA 1638     // int(8*1024*0.2)
#define MQ     9830     // 8*1024 + 1638
#define KK     16

// ---------------- FPS: one block per cloud ----------------
// 512 threads, 8 points/thread held in registers. One barrier per step via
// double-buffered cross-wave reduction slots. Bitwise-matches jax:
// d = ((dx*dx + dy*dy) + dz*dz) in f32, no FMA contraction; argmax ties -> lowest index.
__global__ __launch_bounds__(512) void fps_kernel(const float* __restrict__ pos,
                                                  int* __restrict__ picks) {
#pragma clang fp contract(off)
    __shared__ float sx[NPTS], sy[NPTS], sz[NPTS];
    __shared__ float redv[2][8];
    __shared__ int   redi[2][8];
    const int b = blockIdx.x;
    const int t = threadIdx.x;
    const float* cp = pos + (size_t)b * NPTS * 3;
    for (int i = t; i < NPTS * 3; i += 512) {
        float v = cp[i];
        int p = i / 3, c = i - p * 3;
        if (c == 0) sx[p] = v;
        else if (c == 1) sy[p] = v;
        else sz[p] = v;
    }
    __syncthreads();
    float X[8], Y[8], Z[8], MD[8];
#pragma unroll
    for (int j = 0; j < 8; ++j) {
        int p = j * 512 + t;
        X[j] = sx[p]; Y[j] = sy[p]; Z[j] = sz[p];
        MD[j] = INFINITY;
    }
    if (t == 0) picks[b * M1] = 0;
    int best = 0;
    const int w = t >> 6;
    const int lane = t & 63;
    for (int s = 1; s < M1; ++s) {
        const int par = s & 1;
        // broadcast position of last pick (same-address LDS reads)
        float xl = sx[best], yl = sy[best], zl = sz[best];
        float lv = -INFINITY; int li = 0;
#pragma unroll
        for (int j = 0; j < 8; ++j) {
            float dx = X[j] - xl, dy = Y[j] - yl, dz = Z[j] - zl;
            float d = dx * dx + dy * dy + dz * dz;   // contract(off): no fma
            float m = MD[j] < d ? MD[j] : d;         // jnp.minimum (no NaNs here)
            MD[j] = m;
            // strictly-greater keeps lowest point index (p ascends with j)
            if (m > lv) { lv = m; li = j * 512 + t; }
        }
        // wave-level argmax, tie -> lowest index
#pragma unroll
        for (int off = 32; off > 0; off >>= 1) {
            float ov = __shfl_xor(lv, off, 64);
            int   oi = __shfl_xor(li, off, 64);
            if (ov > lv || (ov == lv && oi < li)) { lv = ov; li = oi; }
        }
        if (lane == 0) { redv[par][w] = lv; redi[par][w] = li; }
        __syncthreads();
        // every thread reduces the 8 wave results (broadcast reads, no 2nd barrier:
        // next iter writes the other parity slot)
        float bv = redv[par][0]; int bi = redi[par][0];
#pragma unroll
        for (int k = 1; k < 8; ++k) {
            float ov = redv[par][k]; int oi = redi[par][k];
            if (ov > bv || (ov == bv && oi < bi)) { bv = ov; bi = oi; }
        }
        best = bi;
        if (t == 0) picks[b * M1 + s] = bi;
    }
}

// ---------------- build combined_idx + row ----------------
__global__ __launch_bounds__(256) void build_kernel(const int* __restrict__ picks,
                                                    int* __restrict__ out) {
    int i = blockIdx.x * 256 + threadIdx.x;
    if (i < MQ) {
        int v;
        if (i < NB * M1) {
            int b = i >> 10;                       // / M1
            v = b * NPTS + picks[i];
        } else {
            int e = i - NB * M1;                   // 0..1637
            int b = e / M2;                        // 0 or 1
            int j = e - b * M2;
            v = b * NPTS + picks[b * M1 + j];      // extra = prefix of base FPS
        }
        out[i] = v;
    }
    if (i < MQ * KK) {
        out[MQ + i] = i >> 4;                      // row = repeat(arange(MQ), 16)
    }
}

// ---------------- kNN: one wave per query ----------------
// 64 dists/lane in registers; 16 rounds of wave argmin (ties -> lowest index),
// excluded slots tracked in a per-lane bitmask (all register indices static).
__global__ __launch_bounds__(256) void knn_kernel(const float* __restrict__ pos,
                                                  int* __restrict__ out) {
#pragma clang fp contract(off)
    const int q = blockIdx.x * 4 + (threadIdx.x >> 6);
    const int l = threadIdx.x & 63;
    if (q >= MQ) return;
    const int cidx = out[q];                 // combined_idx[q] (written by build_kernel)
    const int qb = cidx >> 12;               // / NPTS
    const float qx = pos[(size_t)cidx * 3 + 0];
    const float qy = pos[(size_t)cidx * 3 + 1];
    const float qz = pos[(size_t)cidx * 3 + 2];
    const float* cp = pos + (size_t)qb * NPTS * 3;
    float D[64];
    float lv = INFINITY; int li = 0;
#pragma unroll
    for (int j = 0; j < 64; ++j) {
        int p = j * 64 + l;
        float dx = cp[p * 3 + 0] - qx;
        float dy = cp[p * 3 + 1] - qy;
        float dz = cp[p * 3 + 2] - qz;
        float d = dx * dx + dy * dy + dz * dz;   // contract(off)
        D[j] = d;
        if (d < lv) { lv = d; li = p; }          // strict < keeps lowest index
    }
    unsigned long long mask = 0;
    int* colout = out + MQ + MQ * KK + q * KK;
    for (int r = 0; r < KK; ++r) {
        float bv = lv; int bi = li;
#pragma unroll
        for (int off = 32; off > 0; off >>= 1) {
            float ov = __shfl_xor(bv, off, 64);
            int   oi = __shfl_xor(bi, off, 64);
            if (ov < bv || (ov == bv && oi < bi)) { bv = ov; bi = oi; }
        }
        if (l == 0) colout[r] = qb * NPTS + bi;
        if ((bi & 63) == l) mask |= 1ull << (bi >> 6);  // owner lane masks its slot
        // rebuild local min excluding masked slots (static indices only)
        lv = INFINITY; li = 0;
#pragma unroll
        for (int j = 0; j < 64; ++j) {
            bool act = ((mask >> j) & 1ull) == 0ull;
            float d = D[j];
            if (act && d < lv) { lv = d; li = j * 64 + l; }
        }
    }
}

extern "C" void kernel_launch(void* const* d_in, const int* in_sizes, int n_in,
                              void* d_out, int out_size, void* d_ws, size_t ws_size,
                              hipStream_t stream) {
    const float* pos = (const float*)d_in[0];
    // d_in[1] = batch (sorted, equal clouds) -- implied by layout, unused
    int* picks = (int*)d_ws;                 // 8*1024 int32
    int* out = (int*)d_out;
    fps_kernel<<<NB, 512, 0, stream>>>(pos, picks);
    build_kernel<<<(MQ * KK + 255) / 256, 256, 0, stream>>>(picks, out);
    knn_kernel<<<(MQ + 3) / 4, 256, 0, stream>>>(pos, out);
}

// Round 2
// 785.653 us; speedup vs baseline: 2.0046x; 2.0046x over previous
//
#include <hip/hip_runtime.h>
#include <math.h>

#define NPTS   4096
#define NB     8
#define M1     1024     // ceil(0.25*4096)
#define M2     820      // ceil(0.2*4096)
#define NEXTRA 1638     // int(8*1024*0.2)
#define MQ     9830     // 8*1024 + 1638
#define KK     16

typedef unsigned int u32;
typedef unsigned long long u64;
typedef float f32x2 __attribute__((ext_vector_type(2)));

// DPP lexicographic-MAX combine on (khi_,klo_) u64 key. All-VALU pipe.
// ctrl: 0x121/0x122/0x124/0x128 = row_ror 1/2/4/8 (16-lane butterfly),
// 0x142 = row_bcast15, 0x143 = row_bcast31. old=self -> unsourced lanes no-op.
#define DPP_MAX(CTRL) do {                                                         \
    u32 olo_ = (u32)__builtin_amdgcn_update_dpp((int)klo_, (int)klo_, CTRL, 0xF, 0xF, false); \
    u32 ohi_ = (u32)__builtin_amdgcn_update_dpp((int)khi_, (int)khi_, CTRL, 0xF, 0xF, false); \
    u64 ok_ = ((u64)ohi_ << 32) | olo_;                                            \
    u64 ck_ = ((u64)khi_ << 32) | klo_;                                            \
    if (ok_ > ck_) { klo_ = olo_; khi_ = ohi_; }                                   \
} while (0)

#define DPP_MIN(CTRL) do {                                                         \
    u32 olo_ = (u32)__builtin_amdgcn_update_dpp((int)klo_, (int)klo_, CTRL, 0xF, 0xF, false); \
    u32 ohi_ = (u32)__builtin_amdgcn_update_dpp((int)khi_, (int)khi_, CTRL, 0xF, 0xF, false); \
    u64 ok_ = ((u64)ohi_ << 32) | olo_;                                            \
    u64 ck_ = ((u64)khi_ << 32) | klo_;                                            \
    if (ok_ < ck_) { klo_ = olo_; khi_ = ohi_; }                                   \
} while (0)

// ---------------- FPS: one block (256 thr = 4 waves) per cloud ----------------
// 16 points/thread in registers as 8 f32x2 pairs (v_pk_* math). Wave argmax via
// DPP (VALU pipe), cross-wave via 4 u64 LDS slots + 1 barrier per step.
// Bit-exact vs jax: d = ((dx*dx+dy*dy)+dz*dz) f32 no-contract; argmax tie -> lowest idx
// (u64 key = dist_bits<<32 | ~idx, max-reduced).
__global__ __launch_bounds__(256) void fps_kernel(const float* __restrict__ pos,
                                                  int* __restrict__ picks) {
#pragma clang fp contract(off)
    __shared__ float sx[NPTS], sy[NPTS], sz[NPTS];
    __shared__ u32 slo[2][4], shi[2][4];
    const int b = blockIdx.x;
    const int t = threadIdx.x;
    const float* cp = pos + (size_t)b * NPTS * 3;
    for (int i = t; i < NPTS * 3; i += 256) {
        float v = cp[i];
        int p = i / 3, c = i - p * 3;
        if (c == 0) sx[p] = v;
        else if (c == 1) sy[p] = v;
        else sz[p] = v;
    }
    __syncthreads();

    f32x2 X[8], Y[8], Z[8], MD[8];
    u32 klo[16];
#pragma unroll
    for (int r = 0; r < 8; ++r) {
        int p0 = (2 * r) * 256 + t, p1 = p0 + 256;
        X[r] = f32x2{sx[p0], sx[p1]};
        Y[r] = f32x2{sy[p0], sy[p1]};
        Z[r] = f32x2{sz[p0], sz[p1]};
        MD[r] = f32x2{__builtin_inff(), __builtin_inff()};
    }
#pragma unroll
    for (int j = 0; j < 16; ++j) klo[j] = ~(u32)(j * 256 + t);

    if (t == 0) picks[b * M1] = 0;
    float xl = sx[0], yl = sy[0], zl = sz[0];
    const int wave = t >> 6;

    for (int s = 1; s < M1; ++s) {
        const int par = s & 1;
        const f32x2 xl2 = f32x2{xl, xl};
        const f32x2 yl2 = f32x2{yl, yl};
        const f32x2 zl2 = f32x2{zl, zl};
        u64 kk[16];
#pragma unroll
        for (int r = 0; r < 8; ++r) {
            f32x2 dx = X[r] - xl2;
            f32x2 dy = Y[r] - yl2;
            f32x2 dz = Z[r] - zl2;
            f32x2 d = (dx * dx + dy * dy) + dz * dz;   // contract(off): no fma
            f32x2 m = __builtin_elementwise_min(MD[r], d);  // v_pk_min_f32
            MD[r] = m;
            kk[2 * r]     = ((u64)__float_as_uint(m[0]) << 32) | klo[2 * r];
            kk[2 * r + 1] = ((u64)__float_as_uint(m[1]) << 32) | klo[2 * r + 1];
        }
        // per-lane max tree (static indices; lex key handles tie -> lowest idx)
#pragma unroll
        for (int st = 8; st >= 1; st >>= 1) {
#pragma unroll
            for (int i = 0; i < 16; ++i) {
                if (i < st) { if (kk[i + st] > kk[i]) kk[i] = kk[i + st]; }
            }
        }
        u32 klo_ = (u32)kk[0], khi_ = (u32)(kk[0] >> 32);
        // wave64 max-reduce, VALU pipe; result valid in lane 63
        DPP_MAX(0x121); DPP_MAX(0x122); DPP_MAX(0x124); DPP_MAX(0x128);
        DPP_MAX(0x142); DPP_MAX(0x143);
        u32 wlo = (u32)__builtin_amdgcn_readlane((int)klo_, 63);
        u32 whi = (u32)__builtin_amdgcn_readlane((int)khi_, 63);
        if ((t & 63) == 0) { slo[par][wave] = wlo; shi[par][wave] = whi; }
        __syncthreads();
        u64 bk = ((u64)shi[par][0] << 32) | slo[par][0];
#pragma unroll
        for (int wv = 1; wv < 4; ++wv) {
            u64 ok = ((u64)shi[par][wv] << 32) | slo[par][wv];
            if (ok > bk) bk = ok;
        }
        const int best = (int)(~(u32)bk);
        xl = sx[best]; yl = sy[best]; zl = sz[best];   // broadcast LDS reads
        if (t == 0) picks[b * M1 + s] = best;
    }
}

// ---------------- build combined_idx + row ----------------
__global__ __launch_bounds__(256) void build_kernel(const int* __restrict__ picks,
                                                    int* __restrict__ out) {
    int i = blockIdx.x * 256 + threadIdx.x;
    if (i < MQ) {
        int v;
        if (i < NB * M1) {
            int b = i >> 10;
            v = b * NPTS + picks[i];
        } else {
            int e = i - NB * M1;
            int b = e / M2;
            int j = e - b * M2;
            v = b * NPTS + picks[b * M1 + j];      // extra = prefix of base FPS
        }
        out[i] = v;
    }
    if (i < MQ * KK) {
        out[MQ + i] = i >> 4;                      // row = repeat(arange(MQ), 16)
    }
}

// ---------------- kNN: one wave per query ----------------
// 64 dists/lane in registers; 16 rounds of wave argmin via DPP (ties -> lowest
// index; key = dist_bits<<32 | idx, min-reduced), masked rescan per round.
__global__ __launch_bounds__(256) void knn_kernel(const float* __restrict__ pos,
                                                  int* __restrict__ out) {
#pragma clang fp contract(off)
    const int q = blockIdx.x * 4 + (threadIdx.x >> 6);
    const int l = threadIdx.x & 63;
    if (q >= MQ) return;
    const int cidx = out[q];                 // combined_idx[q] (from build_kernel)
    const int qb = cidx >> 12;
    const float qx = pos[(size_t)cidx * 3 + 0];
    const float qy = pos[(size_t)cidx * 3 + 1];
    const float qz = pos[(size_t)cidx * 3 + 2];
    const float* cp = pos + (size_t)qb * NPTS * 3;
    float D[64];
    float lv = __builtin_inff(); int li = 0;
#pragma unroll
    for (int j = 0; j < 64; ++j) {
        int p = j * 64 + l;
        float dx = cp[p * 3 + 0] - qx;
        float dy = cp[p * 3 + 1] - qy;
        float dz = cp[p * 3 + 2] - qz;
        float d = dx * dx + dy * dy + dz * dz;   // contract(off)
        D[j] = d;
        if (d < lv) { lv = d; li = p; }          // strict < keeps lowest index
    }
    unsigned long long mask = 0;
    int* colout = out + MQ + MQ * KK + q * KK;
    for (int r = 0; r < KK; ++r) {
        u32 klo_ = (u32)li, khi_ = __float_as_uint(lv);
        DPP_MIN(0x121); DPP_MIN(0x122); DPP_MIN(0x124); DPP_MIN(0x128);
        DPP_MIN(0x142); DPP_MIN(0x143);
        u32 bi = (u32)__builtin_amdgcn_readlane((int)klo_, 63);
        if (l == 0) colout[r] = qb * NPTS + (int)bi;
        if ((bi & 63) == (u32)l) mask |= 1ull << (bi >> 6);  // owner masks its slot
        lv = __builtin_inff(); li = 0;
#pragma unroll
        for (int j = 0; j < 64; ++j) {
            bool act = ((mask >> j) & 1ull) == 0ull;
            float d = D[j];
            if (act && d < lv) { lv = d; li = j * 64 + l; }
        }
    }
}

extern "C" void kernel_launch(void* const* d_in, const int* in_sizes, int n_in,
                              void* d_out, int out_size, void* d_ws, size_t ws_size,
                              hipStream_t stream) {
    const float* pos = (const float*)d_in[0];
    int* picks = (int*)d_ws;                 // 8*1024 int32
    int* out = (int*)d_out;
    fps_kernel<<<NB, 256, 0, stream>>>(pos, picks);
    build_kernel<<<(MQ * KK + 255) / 256, 256, 0, stream>>>(picks, out);
    knn_kernel<<<(MQ + 3) / 4, 256, 0, stream>>>(pos, out);
}